// Round 2
// baseline (374.204 us; speedup 1.0000x reference)
//
#include <hip/hip_runtime.h>

#define B_ 4
#define C_ 192
#define S_ 64
#define L_ 512

typedef _Float16 h8 __attribute__((ext_vector_type(8)));
typedef _Float16 h4 __attribute__((ext_vector_type(4)));
typedef _Float16 h2 __attribute__((ext_vector_type(2)));
typedef float f4 __attribute__((ext_vector_type(4)));

// swizzle: phys f16 index within [l][c] tile (64 x 192), stride 192, group-XOR
__device__ __forceinline__ int swz_l(int l) { return ((l >> 2) ^ l) & 7; }

// ---------------- K0: weights f32 -> f16 copies + f32 bias copies + wk^T ---
__global__ __launch_bounds__(512) void k_prep(
    const float* __restrict__ W, const float* __restrict__ Bi,
    const float* __restrict__ Wo, const float* __restrict__ Bo,
    _Float16* __restrict__ wvh, _Float16* __restrict__ woh,
    float* __restrict__ bvf, float* __restrict__ bof,
    float* __restrict__ wkT)
{
    int n = blockIdx.x * 512 + threadIdx.x;
    if (n < 36864)       wvh[n] = (_Float16)W[37056 + n];        // rows 1+C..1+2C-1
    else if (n < 73728)  woh[n - 36864] = (_Float16)Wo[n - 36864];
    else if (n < 73920)  bvf[n - 73728] = Bi[1 + C_ + (n - 73728)];
    else if (n < 74112)  bof[n - 73920] = Bo[n - 73920];
    else if (n < 110976) {                                       // wkT[c][o] = wk[o][c]
        int m = n - 74112;
        int c = m / C_, o = m - c * C_;
        wkT[m] = W[(1 + o) * C_ + c];
    }
}

// ---------------- KA: fused q-dot + softmax + kbar + ctx  ------------------
// grid = B*S = 256 blocks, 512 threads (8 waves). One block per (b,s).
__global__ __launch_bounds__(512) void kA_front(
    const float* __restrict__ Q, const float* __restrict__ K,
    const float* __restrict__ W, const float* __restrict__ Bi,
    const float* __restrict__ wkT, float* __restrict__ ctxb)
{
    __shared__ __attribute__((aligned(16))) float sm_part[4 * 512]; // [cg][l]
    __shared__ float sm_p[512];
    __shared__ float sm_kbar[C_];
    __shared__ float sm_red[8];
    __shared__ float sm_red2[8];

    const int t = threadIdx.x;
    const int b = blockIdx.x >> 6, s = blockIdx.x & 63;
    const int lane = t & 63, w = t >> 6;

    // ---- phase 1: q[l] = wq . Q[b,:,s,l], vectorized f4, c split 4-way ----
    {
        const int qid = t & 127;          // l-quad index (l = qid*4..+3)
        const int cg  = t >> 7;           // c-group 0..3 (48 c each)
        const float* qp = Q + (((size_t)b * C_ + cg * 48) * S_ + s) * L_ + qid * 4;
        f4 a; a[0] = 0.f; a[1] = 0.f; a[2] = 0.f; a[3] = 0.f;
#pragma unroll 4
        for (int c = 0; c < 48; ++c) {
            float wq = W[cg * 48 + c];    // wave-uniform scalar load (row 0 = wq)
            f4 x = *(const f4*)(qp + (size_t)c * (S_ * L_));
            a[0] += wq * x[0]; a[1] += wq * x[1]; a[2] += wq * x[2]; a[3] += wq * x[3];
        }
        *(f4*)&sm_part[cg * 512 + qid * 4] = a;
    }
    __syncthreads();

    // ---- phase 2: softmax over l (thread t owns l = t) --------------------
    float q = (sm_part[t] + sm_part[512 + t]) + (sm_part[1024 + t] + sm_part[1536 + t]);

    float m = q;
#pragma unroll
    for (int off = 32; off >= 1; off >>= 1) m = fmaxf(m, __shfl_down(m, off));
    if (lane == 0) sm_red[w] = m;
    __syncthreads();
    float bm = sm_red[0];
#pragma unroll
    for (int i = 1; i < 8; ++i) bm = fmaxf(bm, sm_red[i]);
    float e = __expf(q - bm);
    float sum = e;
#pragma unroll
    for (int off = 32; off >= 1; off >>= 1) sum += __shfl_down(sum, off);
    if (lane == 0) sm_red2[w] = sum;
    __syncthreads();
    float tot = 0.f;
#pragma unroll
    for (int i = 0; i < 8; ++i) tot += sm_red2[i];
    sm_p[t] = e / tot;
    __syncthreads();

    // ---- phase 3: kbar[c] = sum_l K[b,c,s,l] * p[l]; wave w owns 24 c -----
    {
        const f4* pp = (const f4*)sm_p;
        f4 p0 = pp[lane], p1 = pp[lane + 64];
#pragma unroll 4
        for (int r = 0; r < 24; ++r) {
            int c = w * 24 + r;
            const f4* kp = (const f4*)(K + (((size_t)b * C_ + c) * S_ + s) * L_);
            f4 x0 = kp[lane], x1 = kp[lane + 64];
            float d = x0[0]*p0[0] + x0[1]*p0[1] + x0[2]*p0[2] + x0[3]*p0[3]
                    + x1[0]*p1[0] + x1[1]*p1[1] + x1[2]*p1[2] + x1[3]*p1[3];
#pragma unroll
            for (int off = 32; off >= 1; off >>= 1) d += __shfl_down(d, off);
            if (lane == 0) sm_kbar[c] = d;
        }
    }
    __syncthreads();

    // ---- phase 4: ctx[o] = wk[o,:] . kbar + bk[o], coalesced via wkT ------
    if (t < C_) {
        float a0 = 0.f, a1 = 0.f, a2 = 0.f, a3 = 0.f;
        for (int c = 0; c < C_; c += 4) {
            a0 += wkT[(c + 0) * C_ + t] * sm_kbar[c + 0];
            a1 += wkT[(c + 1) * C_ + t] * sm_kbar[c + 1];
            a2 += wkT[(c + 2) * C_ + t] * sm_kbar[c + 2];
            a3 += wkT[(c + 3) * C_ + t] * sm_kbar[c + 3];
        }
        ctxb[(size_t)blockIdx.x * C_ + t] = (a0 + a1) + (a2 + a3) + Bi[1 + t];
    }
}

// ---------------- K4: MFMA main: out = wo @ (ctx*relu(wv@V+bv)) + bo -------
// grid = 256*(L/64) = 2048 blocks; 512 thr (8 waves). Per block: 192x64 tile.
// Weights consumed as per-lane register fragments straight from global (L2-hot):
// no sm_w, only 2 barriers per block.
__global__ __launch_bounds__(512, 4) void k_main(
    const float* __restrict__ V,
    const _Float16* __restrict__ wvh,
    const _Float16* __restrict__ woh,
    const float* __restrict__ ctxb,
    const float* __restrict__ bvf,
    const float* __restrict__ bof,
    float* __restrict__ Out)
{
    __shared__ __attribute__((aligned(16))) _Float16 sm_v[64 * 192];  // 24576 B
    __shared__ __attribute__((aligned(16))) _Float16 sm_u[64 * 192];  // 24576 B

    const int t = threadIdx.x;
    const int bs = blockIdx.x >> 3;
    const int chunk = blockIdx.x & 7;
    const int b = bs >> 6, s = bs & 63;
    const int l0 = chunk * 64;
    const int w = t >> 6, lane = t & 63;
    const int quad = lane >> 4, n16 = lane & 15;

    // ---- stage V chunk: f32 -> f16, transpose to [l][c] swizzled ----------
    {
        const int tx = t & 15, rp = t >> 4;              // rp 0..31
        h2* smv2 = (h2*)sm_v;                            // dword granularity
#pragma unroll
        for (int i = 0; i < 3; ++i) {
            int cp = i * 32 + rp;                        // c = 2cp, 2cp+1
            const float* vp = V + ((size_t)(b * C_ + 2 * cp) * S_ + s) * L_ + l0 + tx * 4;
            f4 x0 = *(const f4*)vp;
            f4 x1 = *(const f4*)(vp + S_ * L_);
#pragma unroll
            for (int k = 0; k < 4; ++k) {
                int l = tx * 4 + k;
                int dw = l * 96 + (((cp >> 2) ^ swz_l(l)) << 2) + (cp & 3);
                h2 hh; hh[0] = (_Float16)x0[k]; hh[1] = (_Float16)x1[k];
                smv2[dw] = hh;
            }
        }
    }
    __syncthreads();

    const int oB = (w & 3) * 48;      // 48-row o/p slice of this wave
    const int lB = (w >> 2) * 32;     // 32-row l slice of this wave

    // =================== GEMM1: v[o,l] = Wv @ V ============================
    f4 acc[3][2];
#pragma unroll
    for (int i = 0; i < 3; ++i)
#pragma unroll
        for (int j = 0; j < 2; ++j) acc[i][j] = (f4)0.f;

#pragma unroll
    for (int kt = 0; kt < 6; ++kt) {
        h8 afr[3];
#pragma unroll
        for (int i = 0; i < 3; ++i)
            afr[i] = *(const h8*)(wvh + (size_t)(oB + i * 16 + n16) * C_ + kt * 32 + quad * 8);
        h8 bfr[2];
#pragma unroll
        for (int j = 0; j < 2; ++j) {
            int l = lB + j * 16 + n16;
            bfr[j] = *(const h8*)(sm_v + l * 192 + (((kt * 4 + quad) ^ swz_l(l)) << 3));
        }
#pragma unroll
        for (int i = 0; i < 3; ++i)
#pragma unroll
            for (int j = 0; j < 2; ++j)
                acc[i][j] = __builtin_amdgcn_mfma_f32_16x16x32_f16(afr[i], bfr[j], acc[i][j], 0, 0, 0);
    }

    // ---- epilogue 1: u = ctx * relu(v + bv) -> sm_u [l][o] swizzled -------
#pragma unroll
    for (int i = 0; i < 3; ++i) {
        int o0 = oB + i * 16 + quad * 4;
        f4 cx = *(const f4*)(ctxb + (size_t)bs * C_ + o0);
        f4 bv = *(const f4*)(bvf + o0);
#pragma unroll
        for (int j = 0; j < 2; ++j) {
            int l = lB + j * 16 + n16;
            h4 uu;
#pragma unroll
            for (int r = 0; r < 4; ++r) {
                float v = acc[i][j][r] + bv[r];
                uu[r] = (_Float16)(fmaxf(v, 0.f) * cx[r]);
            }
            *(h4*)(sm_u + l * 192 + (((o0 >> 3) ^ swz_l(l)) << 3) + (o0 & 7)) = uu;
        }
    }
    __syncthreads();

    // =================== GEMM2: out[l,p] = u^T @ Wo^T ======================
    f4 acc2[2][3];
#pragma unroll
    for (int i = 0; i < 2; ++i)
#pragma unroll
        for (int j = 0; j < 3; ++j) acc2[i][j] = (f4)0.f;

#pragma unroll
    for (int kt = 0; kt < 6; ++kt) {
        h8 bfr2[3];
#pragma unroll
        for (int j = 0; j < 3; ++j)
            bfr2[j] = *(const h8*)(woh + (size_t)(oB + j * 16 + n16) * C_ + kt * 32 + quad * 8);
        h8 afr2[2];
#pragma unroll
        for (int i = 0; i < 2; ++i) {
            int l = lB + i * 16 + n16;
            afr2[i] = *(const h8*)(sm_u + l * 192 + (((kt * 4 + quad) ^ swz_l(l)) << 3));
        }
#pragma unroll
        for (int j = 0; j < 3; ++j)
#pragma unroll
            for (int i = 0; i < 2; ++i)
                acc2[i][j] = __builtin_amdgcn_mfma_f32_16x16x32_f16(afr2[i], bfr2[j], acc2[i][j], 0, 0, 0);
    }

    // ---- epilogue 2: + bo, float4 stores ----------------------------------
#pragma unroll
    for (int j = 0; j < 3; ++j) {
        int p = oB + j * 16 + n16;
        float bo = bof[p];
        float* obase = Out + ((size_t)(b * C_ + p) * S_ + s) * L_ + l0;
#pragma unroll
        for (int i = 0; i < 2; ++i) {
            int l = lB + i * 16 + quad * 4;
            f4 ov = acc2[i][j];
            ov[0] += bo; ov[1] += bo; ov[2] += bo; ov[3] += bo;
            *(f4*)(obase + l) = ov;
        }
    }
}

extern "C" void kernel_launch(void* const* d_in, const int* in_sizes, int n_in,
                              void* d_out, int out_size, void* d_ws, size_t ws_size,
                              hipStream_t stream) {
    const float* Q  = (const float*)d_in[0];
    const float* K  = (const float*)d_in[1];
    const float* V  = (const float*)d_in[2];
    const float* W  = (const float*)d_in[3];
    const float* Bi = (const float*)d_in[4];
    const float* Wo = (const float*)d_in[5];
    const float* Bo = (const float*)d_in[6];
    float* Out = (float*)d_out;

    char* ws = (char*)d_ws;
    _Float16* wvh = (_Float16*)(ws);                 // 73728 B
    _Float16* woh = (_Float16*)(ws + 73728);         // 73728 B -> 147456
    float*    bvf = (float*)(ws + 147456);           // 768 B   -> 148224
    float*    bof = (float*)(ws + 148224);           // 768 B   -> 148992
    float*    wkT = (float*)(ws + 148992);           // 147456 B-> 296448
    float*    ctxb = (float*)(ws + 296448);          // 196608 B-> 493056

    k_prep  <<<dim3(217),     dim3(512), 0, stream>>>(W, Bi, Wo, Bo, wvh, woh, bvf, bof, wkT);
    kA_front<<<dim3(B_ * S_), dim3(512), 0, stream>>>(Q, K, W, Bi, wkT, ctxb);
    k_main  <<<dim3(B_*S_*8), dim3(512), 0, stream>>>(V, wvh, woh, ctxb, bvf, bof, Out);
}

// Round 3
// 372.810 us; speedup vs baseline: 1.0037x; 1.0037x over previous
//
#include <hip/hip_runtime.h>

#define B_ 4
#define C_ 192
#define S_ 64
#define L_ 512

typedef _Float16 h8 __attribute__((ext_vector_type(8)));
typedef _Float16 h4 __attribute__((ext_vector_type(4)));
typedef _Float16 h2 __attribute__((ext_vector_type(2)));
typedef float f4 __attribute__((ext_vector_type(4)));

// swizzle: phys f16 index within [l][c] tile (64 x 192), stride 192, group-XOR
__device__ __forceinline__ int swz_l(int l) { return ((l >> 2) ^ l) & 7; }

// ---------------- K0: weights f32 -> f16 copies + f32 bias copies + wk^T ---
__global__ __launch_bounds__(512) void k_prep(
    const float* __restrict__ W, const float* __restrict__ Bi,
    const float* __restrict__ Wo, const float* __restrict__ Bo,
    _Float16* __restrict__ wvh, _Float16* __restrict__ woh,
    float* __restrict__ bvf, float* __restrict__ bof,
    float* __restrict__ wkT)
{
    int n = blockIdx.x * 512 + threadIdx.x;
    if (n < 36864)       wvh[n] = (_Float16)W[37056 + n];        // rows 1+C..1+2C-1
    else if (n < 73728)  woh[n - 36864] = (_Float16)Wo[n - 36864];
    else if (n < 73920)  bvf[n - 73728] = Bi[1 + C_ + (n - 73728)];
    else if (n < 74112)  bof[n - 73920] = Bo[n - 73920];
    else if (n < 110976) {                                       // wkT[c][o] = wk[o][c]
        int m = n - 74112;
        int c = m / C_, o = m - c * C_;
        wkT[m] = W[(1 + o) * C_ + c];
    }
}

// ---------------- KA: fused q-dot + softmax + kbar + ctx  ------------------
// grid = B*S = 256 blocks, 1024 threads (16 waves) -> 50% occupancy at 1 blk/CU.
__global__ __launch_bounds__(1024) void kA_front(
    const float* __restrict__ Q, const float* __restrict__ K,
    const float* __restrict__ W, const float* __restrict__ Bi,
    const float* __restrict__ wkT, float* __restrict__ ctxb)
{
    __shared__ __attribute__((aligned(16))) float sm_part[8 * 512]; // [cg][l]
    __shared__ float sm_p[512];
    __shared__ float sm_kbar[C_];
    __shared__ float sm_red[8];
    __shared__ float sm_red2[8];

    const int t = threadIdx.x;
    const int b = blockIdx.x >> 6, s = blockIdx.x & 63;
    const int lane = t & 63, w = t >> 6;

    // ---- phase 1: q[l] = wq . Q[b,:,s,l], vectorized f4, c split 8-way ----
    {
        const int qid = t & 127;          // l-quad index (l = qid*4..+3)
        const int cg  = t >> 7;           // c-group 0..7 (24 c each)
        const float* qp = Q + (((size_t)b * C_ + cg * 24) * S_ + s) * L_ + qid * 4;
        f4 a; a[0] = 0.f; a[1] = 0.f; a[2] = 0.f; a[3] = 0.f;
#pragma unroll 8
        for (int c = 0; c < 24; ++c) {
            float wq = W[cg * 24 + c];    // wave-uniform scalar load (row 0 = wq)
            f4 x = *(const f4*)(qp + (size_t)c * (S_ * L_));
            a[0] += wq * x[0]; a[1] += wq * x[1]; a[2] += wq * x[2]; a[3] += wq * x[3];
        }
        *(f4*)&sm_part[cg * 512 + qid * 4] = a;
    }
    __syncthreads();

    // ---- phase 2: softmax over l (thread t<512 owns l = t) ----------------
    float q = 0.f, e = 0.f;
    if (t < 512) {
        q = ((sm_part[t] + sm_part[512 + t]) + (sm_part[1024 + t] + sm_part[1536 + t]))
          + ((sm_part[2048 + t] + sm_part[2560 + t]) + (sm_part[3072 + t] + sm_part[3584 + t]));
        float m = q;
#pragma unroll
        for (int off = 32; off >= 1; off >>= 1) m = fmaxf(m, __shfl_down(m, off));
        if (lane == 0) sm_red[w] = m;
    }
    __syncthreads();
    if (t < 512) {
        float bm = sm_red[0];
#pragma unroll
        for (int i = 1; i < 8; ++i) bm = fmaxf(bm, sm_red[i]);
        e = __expf(q - bm);
        float sum = e;
#pragma unroll
        for (int off = 32; off >= 1; off >>= 1) sum += __shfl_down(sum, off);
        if (lane == 0) sm_red2[w] = sum;
    }
    __syncthreads();
    if (t < 512) {
        float tot = 0.f;
#pragma unroll
        for (int i = 0; i < 8; ++i) tot += sm_red2[i];
        sm_p[t] = e / tot;
    }
    __syncthreads();

    // ---- phase 3: kbar[c] = sum_l K[b,c,s,l] * p[l]; wave w owns 12 c -----
    {
        const f4* pp = (const f4*)sm_p;
        f4 p0 = pp[lane], p1 = pp[lane + 64];
#pragma unroll 4
        for (int r = 0; r < 12; ++r) {
            int c = w * 12 + r;
            const f4* kp = (const f4*)(K + (((size_t)b * C_ + c) * S_ + s) * L_);
            f4 x0 = kp[lane], x1 = kp[lane + 64];
            float d = x0[0]*p0[0] + x0[1]*p0[1] + x0[2]*p0[2] + x0[3]*p0[3]
                    + x1[0]*p1[0] + x1[1]*p1[1] + x1[2]*p1[2] + x1[3]*p1[3];
#pragma unroll
            for (int off = 32; off >= 1; off >>= 1) d += __shfl_down(d, off);
            if (lane == 0) sm_kbar[c] = d;
        }
    }
    __syncthreads();

    // ---- phase 4: ctx[o] = wk[o,:] . kbar + bk[o], coalesced via wkT ------
    if (t < C_) {
        float a0 = 0.f, a1 = 0.f, a2 = 0.f, a3 = 0.f;
        for (int c = 0; c < C_; c += 4) {
            a0 += wkT[(c + 0) * C_ + t] * sm_kbar[c + 0];
            a1 += wkT[(c + 1) * C_ + t] * sm_kbar[c + 1];
            a2 += wkT[(c + 2) * C_ + t] * sm_kbar[c + 2];
            a3 += wkT[(c + 3) * C_ + t] * sm_kbar[c + 3];
        }
        ctxb[(size_t)blockIdx.x * C_ + t] = (a0 + a1) + (a2 + a3) + Bi[1 + t];
    }
}

// ---------------- K4: MFMA main: out = wo @ (ctx*relu(wv@V+bv)) + bo -------
// grid = 256*(L/64) = 2048 blocks; 512 thr (8 waves). Per block: 192x64 tile.
// Weights hoisted into registers ONCE per block (18 x h8 = 72 VGPR per GEMM),
// so kt-loops are pure ds_read_b128 + MFMA. Only 2 barriers per block.
__global__ __launch_bounds__(512, 4) void k_main(
    const float* __restrict__ V,
    const _Float16* __restrict__ wvh,
    const _Float16* __restrict__ woh,
    const float* __restrict__ ctxb,
    const float* __restrict__ bvf,
    const float* __restrict__ bof,
    float* __restrict__ Out)
{
    __shared__ __attribute__((aligned(16))) _Float16 sm_v[64 * 192];  // 24576 B
    __shared__ __attribute__((aligned(16))) _Float16 sm_u[64 * 192];  // 24576 B

    const int t = threadIdx.x;
    const int bs = blockIdx.x >> 3;
    const int chunk = blockIdx.x & 7;
    const int b = bs >> 6, s = bs & 63;
    const int l0 = chunk * 64;
    const int w = t >> 6, lane = t & 63;
    const int quad = lane >> 4, n16 = lane & 15;

    const int oB = (w & 3) * 48;      // 48-row o/p slice of this wave
    const int lB = (w >> 2) * 32;     // 32-row l slice of this wave

    // ---- stage V chunk: f32 -> f16, transpose to [l][c] swizzled ----------
    {
        const int tx = t & 15, rp = t >> 4;              // rp 0..31
        h2* smv2 = (h2*)sm_v;                            // dword granularity
#pragma unroll
        for (int i = 0; i < 3; ++i) {
            int cp = i * 32 + rp;                        // c = 2cp, 2cp+1
            const float* vp = V + ((size_t)(b * C_ + 2 * cp) * S_ + s) * L_ + l0 + tx * 4;
            f4 x0 = *(const f4*)vp;
            f4 x1 = *(const f4*)(vp + S_ * L_);
#pragma unroll
            for (int k = 0; k < 4; ++k) {
                int l = tx * 4 + k;
                int dw = l * 96 + (((cp >> 2) ^ swz_l(l)) << 2) + (cp & 3);
                h2 hh; hh[0] = (_Float16)x0[k]; hh[1] = (_Float16)x1[k];
                smv2[dw] = hh;
            }
        }
    }

    // ---- hoist ALL Wv fragments (18 independent L2 gathers, once/block) ---
    h8 wv_fr[6][3];
#pragma unroll
    for (int kt = 0; kt < 6; ++kt)
#pragma unroll
        for (int i = 0; i < 3; ++i)
            wv_fr[kt][i] = *(const h8*)(wvh + (size_t)(oB + i * 16 + n16) * C_ + kt * 32 + quad * 8);

    __syncthreads();

    // =================== GEMM1: v[o,l] = Wv @ V ============================
    f4 acc[3][2];
#pragma unroll
    for (int i = 0; i < 3; ++i)
#pragma unroll
        for (int j = 0; j < 2; ++j) acc[i][j] = (f4)0.f;

#pragma unroll
    for (int kt = 0; kt < 6; ++kt) {
        h8 bfr[2];
#pragma unroll
        for (int j = 0; j < 2; ++j) {
            int l = lB + j * 16 + n16;
            bfr[j] = *(const h8*)(sm_v + l * 192 + (((kt * 4 + quad) ^ swz_l(l)) << 3));
        }
#pragma unroll
        for (int i = 0; i < 3; ++i)
#pragma unroll
            for (int j = 0; j < 2; ++j)
                acc[i][j] = __builtin_amdgcn_mfma_f32_16x16x32_f16(wv_fr[kt][i], bfr[j], acc[i][j], 0, 0, 0);
    }

    // ---- hoist Wo fragments now: overlaps epilogue-1 VALU + barrier -------
    h8 wo_fr[6][3];
#pragma unroll
    for (int kt = 0; kt < 6; ++kt)
#pragma unroll
        for (int j = 0; j < 3; ++j)
            wo_fr[kt][j] = *(const h8*)(woh + (size_t)(oB + j * 16 + n16) * C_ + kt * 32 + quad * 8);

    // ---- epilogue 1: u = ctx * relu(v + bv) -> sm_u [l][o] swizzled -------
#pragma unroll
    for (int i = 0; i < 3; ++i) {
        int o0 = oB + i * 16 + quad * 4;
        f4 cx = *(const f4*)(ctxb + (size_t)bs * C_ + o0);
        f4 bv = *(const f4*)(bvf + o0);
#pragma unroll
        for (int j = 0; j < 2; ++j) {
            int l = lB + j * 16 + n16;
            h4 uu;
#pragma unroll
            for (int r = 0; r < 4; ++r) {
                float v = acc[i][j][r] + bv[r];
                uu[r] = (_Float16)(fmaxf(v, 0.f) * cx[r]);
            }
            *(h4*)(sm_u + l * 192 + (((o0 >> 3) ^ swz_l(l)) << 3) + (o0 & 7)) = uu;
        }
    }
    __syncthreads();

    // =================== GEMM2: out[l,p] = u^T @ Wo^T ======================
    f4 acc2[2][3];
#pragma unroll
    for (int i = 0; i < 2; ++i)
#pragma unroll
        for (int j = 0; j < 3; ++j) acc2[i][j] = (f4)0.f;

#pragma unroll
    for (int kt = 0; kt < 6; ++kt) {
        h8 afr2[2];
#pragma unroll
        for (int i = 0; i < 2; ++i) {
            int l = lB + i * 16 + n16;
            afr2[i] = *(const h8*)(sm_u + l * 192 + (((kt * 4 + quad) ^ swz_l(l)) << 3));
        }
#pragma unroll
        for (int j = 0; j < 3; ++j)
#pragma unroll
            for (int i = 0; i < 2; ++i)
                acc2[i][j] = __builtin_amdgcn_mfma_f32_16x16x32_f16(afr2[i], wo_fr[kt][j], acc2[i][j], 0, 0, 0);
    }

    // ---- epilogue 2: + bo, float4 stores ----------------------------------
#pragma unroll
    for (int j = 0; j < 3; ++j) {
        int p = oB + j * 16 + n16;
        float bo = bof[p];
        float* obase = Out + ((size_t)(b * C_ + p) * S_ + s) * L_ + l0;
#pragma unroll
        for (int i = 0; i < 2; ++i) {
            int l = lB + i * 16 + quad * 4;
            f4 ov = acc2[i][j];
            ov[0] += bo; ov[1] += bo; ov[2] += bo; ov[3] += bo;
            *(f4*)(obase + l) = ov;
        }
    }
}

extern "C" void kernel_launch(void* const* d_in, const int* in_sizes, int n_in,
                              void* d_out, int out_size, void* d_ws, size_t ws_size,
                              hipStream_t stream) {
    const float* Q  = (const float*)d_in[0];
    const float* K  = (const float*)d_in[1];
    const float* V  = (const float*)d_in[2];
    const float* W  = (const float*)d_in[3];
    const float* Bi = (const float*)d_in[4];
    const float* Wo = (const float*)d_in[5];
    const float* Bo = (const float*)d_in[6];
    float* Out = (float*)d_out;

    char* ws = (char*)d_ws;
    _Float16* wvh = (_Float16*)(ws);                 // 73728 B
    _Float16* woh = (_Float16*)(ws + 73728);         // 73728 B -> 147456
    float*    bvf = (float*)(ws + 147456);           // 768 B   -> 148224
    float*    bof = (float*)(ws + 148224);           // 768 B   -> 148992
    float*    wkT = (float*)(ws + 148992);           // 147456 B-> 296448
    float*    ctxb = (float*)(ws + 296448);          // 196608 B-> 493056

    k_prep  <<<dim3(217),      dim3(512),  0, stream>>>(W, Bi, Wo, Bo, wvh, woh, bvf, bof, wkT);
    kA_front<<<dim3(B_ * S_),  dim3(1024), 0, stream>>>(Q, K, W, Bi, wkT, ctxb);
    k_main  <<<dim3(B_*S_*8),  dim3(512),  0, stream>>>(V, wvh, woh, ctxb, bvf, bof, Out);
}

// Round 5
// 340.882 us; speedup vs baseline: 1.0977x; 1.0937x over previous
//
#include <hip/hip_runtime.h>

#define B_ 4
#define C_ 192
#define S_ 64
#define L_ 512

typedef _Float16 h8 __attribute__((ext_vector_type(8)));
typedef _Float16 h4 __attribute__((ext_vector_type(4)));
typedef _Float16 h2 __attribute__((ext_vector_type(2)));
typedef float f4 __attribute__((ext_vector_type(4)));

// swizzle: phys f16 index within [l][c] tile, stride 192, group-XOR
__device__ __forceinline__ int swz_l(int l) { return ((l >> 2) ^ l) & 7; }

// ---------------- K0: weights f32 -> f16 copies + f32 bias copies + wk^T ---
__global__ __launch_bounds__(512) void k_prep(
    const float* __restrict__ W, const float* __restrict__ Bi,
    const float* __restrict__ Wo, const float* __restrict__ Bo,
    _Float16* __restrict__ wvh, _Float16* __restrict__ woh,
    float* __restrict__ bvf, float* __restrict__ bof,
    float* __restrict__ wkT)
{
    int n = blockIdx.x * 512 + threadIdx.x;
    if (n < 36864)       wvh[n] = (_Float16)W[37056 + n];        // rows 1+C..1+2C-1
    else if (n < 73728)  woh[n - 36864] = (_Float16)Wo[n - 36864];
    else if (n < 73920)  bvf[n - 73728] = Bi[1 + C_ + (n - 73728)];
    else if (n < 74112)  bof[n - 73920] = Bo[n - 73920];
    else if (n < 110976) {                                       // wkT[c][o] = wk[o][c]
        int m = n - 74112;
        int c = m / C_, o = m - c * C_;
        wkT[m] = W[(1 + o) * C_ + c];
    }
}

// ---------------- KA: fused q-dot + softmax + kbar + ctx  ------------------
// grid = B*S = 256 blocks, 1024 threads (16 waves).
__global__ __launch_bounds__(1024) void kA_front(
    const float* __restrict__ Q, const float* __restrict__ K,
    const float* __restrict__ W, const float* __restrict__ Bi,
    const float* __restrict__ wkT, float* __restrict__ ctxb)
{
    __shared__ __attribute__((aligned(16))) float sm_part[8 * 512]; // [cg][l]
    __shared__ float sm_p[512];
    __shared__ float sm_kbar[C_];
    __shared__ float sm_red[8];
    __shared__ float sm_red2[8];

    const int t = threadIdx.x;
    const int b = blockIdx.x >> 6, s = blockIdx.x & 63;
    const int lane = t & 63, w = t >> 6;

    // ---- phase 1: q[l] = wq . Q[b,:,s,l], vectorized f4, c split 8-way ----
    {
        const int qid = t & 127;          // l-quad index (l = qid*4..+3)
        const int cg  = t >> 7;           // c-group 0..7 (24 c each)
        const float* qp = Q + (((size_t)b * C_ + cg * 24) * S_ + s) * L_ + qid * 4;
        f4 a; a[0] = 0.f; a[1] = 0.f; a[2] = 0.f; a[3] = 0.f;
#pragma unroll 8
        for (int c = 0; c < 24; ++c) {
            float wq = W[cg * 24 + c];    // wave-uniform scalar load (row 0 = wq)
            f4 x = *(const f4*)(qp + (size_t)c * (S_ * L_));
            a[0] += wq * x[0]; a[1] += wq * x[1]; a[2] += wq * x[2]; a[3] += wq * x[3];
        }
        *(f4*)&sm_part[cg * 512 + qid * 4] = a;
    }
    __syncthreads();

    // ---- phase 2: softmax over l (thread t<512 owns l = t) ----------------
    float q = 0.f, e = 0.f;
    if (t < 512) {
        q = ((sm_part[t] + sm_part[512 + t]) + (sm_part[1024 + t] + sm_part[1536 + t]))
          + ((sm_part[2048 + t] + sm_part[2560 + t]) + (sm_part[3072 + t] + sm_part[3584 + t]));
        float m = q;
#pragma unroll
        for (int off = 32; off >= 1; off >>= 1) m = fmaxf(m, __shfl_down(m, off));
        if (lane == 0) sm_red[w] = m;
    }
    __syncthreads();
    if (t < 512) {
        float bm = sm_red[0];
#pragma unroll
        for (int i = 1; i < 8; ++i) bm = fmaxf(bm, sm_red[i]);
        e = __expf(q - bm);
        float sum = e;
#pragma unroll
        for (int off = 32; off >= 1; off >>= 1) sum += __shfl_down(sum, off);
        if (lane == 0) sm_red2[w] = sum;
    }
    __syncthreads();
    if (t < 512) {
        float tot = 0.f;
#pragma unroll
        for (int i = 0; i < 8; ++i) tot += sm_red2[i];
        sm_p[t] = e / tot;
    }
    __syncthreads();

    // ---- phase 3: kbar[c] = sum_l K[b,c,s,l] * p[l]; wave w owns 12 c -----
    {
        const f4* pp = (const f4*)sm_p;
        f4 p0 = pp[lane], p1 = pp[lane + 64];
#pragma unroll 4
        for (int r = 0; r < 12; ++r) {
            int c = w * 12 + r;
            const f4* kp = (const f4*)(K + (((size_t)b * C_ + c) * S_ + s) * L_);
            f4 x0 = kp[lane], x1 = kp[lane + 64];
            float d = x0[0]*p0[0] + x0[1]*p0[1] + x0[2]*p0[2] + x0[3]*p0[3]
                    + x1[0]*p1[0] + x1[1]*p1[1] + x1[2]*p1[2] + x1[3]*p1[3];
#pragma unroll
            for (int off = 32; off >= 1; off >>= 1) d += __shfl_down(d, off);
            if (lane == 0) sm_kbar[c] = d;
        }
    }
    __syncthreads();

    // ---- phase 4: ctx[o] = wk[o,:] . kbar + bk[o], coalesced via wkT ------
    if (t < C_) {
        float a0 = 0.f, a1 = 0.f, a2 = 0.f, a3 = 0.f;
        for (int c = 0; c < C_; c += 4) {
            a0 += wkT[(c + 0) * C_ + t] * sm_kbar[c + 0];
            a1 += wkT[(c + 1) * C_ + t] * sm_kbar[c + 1];
            a2 += wkT[(c + 2) * C_ + t] * sm_kbar[c + 2];
            a3 += wkT[(c + 3) * C_ + t] * sm_kbar[c + 3];
        }
        ctxb[(size_t)blockIdx.x * C_ + t] = (a0 + a1) + (a2 + a3) + Bi[1 + t];
    }
}

// ---------------- K4: MFMA main: out = wo @ (ctx*relu(wv@V+bv)) + bo -------
// grid = 256*(L/128) = 1024 blocks; 1024 thr (16 waves). Per block: 192x128.
// FULL weight matrix in LDS (192x200 pad, staged once, reused Wv->Wo);
// V buffer reused for u. 3 barriers/block, zero in-loop staging.
__global__ __launch_bounds__(1024, 4) void k_main(
    const float* __restrict__ V,
    const _Float16* __restrict__ wvh,
    const _Float16* __restrict__ woh,
    const float* __restrict__ ctxb,
    const float* __restrict__ bvf,
    const float* __restrict__ bof,
    float* __restrict__ Out)
{
    __shared__ __attribute__((aligned(16))) _Float16 wbuf[192 * 200];  // 76800 B
    __shared__ __attribute__((aligned(16))) _Float16 vbuf[128 * 192];  // 49152 B (V, then u)

    const int t = threadIdx.x;
    const int bs = blockIdx.x >> 2;
    const int chunk = blockIdx.x & 3;
    const int b = bs >> 6, s = bs & 63;
    const int l0 = chunk * 128;
    const int w = t >> 6, lane = t & 63;
    const int quad = lane >> 4, n16 = lane & 15;

    const int oB = (w & 3) * 48;      // 48-row o/p slice of this wave
    const int lB = (w >> 2) * 32;     // 32-row l slice of this wave

    // ---- stage Wv (full 192x192 f16) into padded LDS, coalesced 16B -------
#pragma unroll
    for (int i = 0; i < 5; ++i) {
        int u = t + i * 1024;                          // 16B units; 4608 total
        if (u < 4608) {
            int r = u / 24, c16 = u - r * 24;
            *(f4*)(wbuf + r * 200 + c16 * 8) = *(const f4*)(wvh + r * 192 + c16 * 8);
        }
    }

    // ---- stage V chunk (128 l): f32 -> f16, transpose to [l][c] swizzled --
    {
        const int tx = t & 31, rp = t >> 5;            // tx: 32 f4-groups = 128 l
        h2* smv2 = (h2*)vbuf;
#pragma unroll
        for (int i = 0; i < 3; ++i) {
            int cp = i * 32 + rp;                      // c = 2cp, 2cp+1
            const float* vp = V + ((size_t)(b * C_ + 2 * cp) * S_ + s) * L_ + l0 + tx * 4;
            f4 x0 = *(const f4*)vp;
            f4 x1 = *(const f4*)(vp + S_ * L_);
#pragma unroll
            for (int k = 0; k < 4; ++k) {
                int l = tx * 4 + k;
                int dw = l * 96 + (((cp >> 2) ^ swz_l(l)) << 2) + (cp & 3);
                h2 hh; hh[0] = (_Float16)x0[k]; hh[1] = (_Float16)x1[k];
                smv2[dw] = hh;
            }
        }
    }

    // ---- hoist epilogue operands (tiny, L2-hot) ---------------------------
    f4 cx[3], bvv[3];
    float bo_r[3];
#pragma unroll
    for (int i = 0; i < 3; ++i) {
        int o0 = oB + i * 16 + quad * 4;
        cx[i]  = *(const f4*)(ctxb + (size_t)bs * C_ + o0);
        bvv[i] = *(const f4*)(bvf + o0);
        bo_r[i] = bof[oB + i * 16 + n16];
    }
    __syncthreads();

    // =================== GEMM1: v[o,l] = Wv @ V ============================
    f4 acc[3][2];
#pragma unroll
    for (int i = 0; i < 3; ++i)
#pragma unroll
        for (int j = 0; j < 2; ++j) acc[i][j] = (f4)0.f;

#pragma unroll
    for (int kt = 0; kt < 6; ++kt) {
        h8 afr[3];
#pragma unroll
        for (int i = 0; i < 3; ++i)
            afr[i] = *(const h8*)(wbuf + (oB + i * 16 + n16) * 200 + kt * 32 + quad * 8);
        h8 bfr[2];
#pragma unroll
        for (int j = 0; j < 2; ++j) {
            int l = lB + j * 16 + n16;
            bfr[j] = *(const h8*)(vbuf + l * 192 + (((kt * 4 + quad) ^ swz_l(l)) << 3));
        }
#pragma unroll
        for (int i = 0; i < 3; ++i)
#pragma unroll
            for (int j = 0; j < 2; ++j)
                acc[i][j] = __builtin_amdgcn_mfma_f32_16x16x32_f16(afr[i], bfr[j], acc[i][j], 0, 0, 0);
    }
    __syncthreads();   // all GEMM1 reads of wbuf/vbuf done

    // ---- stage Wo over Wv; write u = ctx*relu(v+bv) over V ----------------
#pragma unroll
    for (int i = 0; i < 5; ++i) {
        int u = t + i * 1024;
        if (u < 4608) {
            int r = u / 24, c16 = u - r * 24;
            *(f4*)(wbuf + r * 200 + c16 * 8) = *(const f4*)(woh + r * 192 + c16 * 8);
        }
    }
#pragma unroll
    for (int i = 0; i < 3; ++i) {
        int o0 = oB + i * 16 + quad * 4;
#pragma unroll
        for (int j = 0; j < 2; ++j) {
            int l = lB + j * 16 + n16;
            h4 uu;
#pragma unroll
            for (int r = 0; r < 4; ++r) {
                float v = acc[i][j][r] + bvv[i][r];
                uu[r] = (_Float16)(fmaxf(v, 0.f) * cx[i][r]);
            }
            *(h4*)(vbuf + l * 192 + (((o0 >> 3) ^ swz_l(l)) << 3) + (o0 & 7)) = uu;
        }
    }
    __syncthreads();   // Wo + u ready

    // =================== GEMM2: out[l,p] = u^T @ Wo^T ======================
    f4 acc2[2][3];
#pragma unroll
    for (int i = 0; i < 2; ++i)
#pragma unroll
        for (int j = 0; j < 3; ++j) acc2[i][j] = (f4)0.f;

#pragma unroll
    for (int kt = 0; kt < 6; ++kt) {
        h8 afr2[2];
#pragma unroll
        for (int i = 0; i < 2; ++i) {
            int l = lB + i * 16 + n16;
            afr2[i] = *(const h8*)(vbuf + l * 192 + (((kt * 4 + quad) ^ swz_l(l)) << 3));
        }
        h8 bfr2[3];
#pragma unroll
        for (int j = 0; j < 3; ++j)
            bfr2[j] = *(const h8*)(wbuf + (oB + j * 16 + n16) * 200 + kt * 32 + quad * 8);
#pragma unroll
        for (int j = 0; j < 3; ++j)
#pragma unroll
            for (int i = 0; i < 2; ++i)
                acc2[i][j] = __builtin_amdgcn_mfma_f32_16x16x32_f16(afr2[i], bfr2[j], acc2[i][j], 0, 0, 0);
    }

    // ---- epilogue 2: + bo, float4 stores ----------------------------------
#pragma unroll
    for (int j = 0; j < 3; ++j) {
        int p = oB + j * 16 + n16;
        float bo = bo_r[j];
        float* obase = Out + ((size_t)(b * C_ + p) * S_ + s) * L_ + l0;
#pragma unroll
        for (int i = 0; i < 2; ++i) {
            int l = lB + i * 16 + quad * 4;
            f4 ov = acc2[i][j];
            ov[0] += bo; ov[1] += bo; ov[2] += bo; ov[3] += bo;
            *(f4*)(obase + l) = ov;
        }
    }
}

extern "C" void kernel_launch(void* const* d_in, const int* in_sizes, int n_in,
                              void* d_out, int out_size, void* d_ws, size_t ws_size,
                              hipStream_t stream) {
    const float* Q  = (const float*)d_in[0];
    const float* K  = (const float*)d_in[1];
    const float* V  = (const float*)d_in[2];
    const float* W  = (const float*)d_in[3];
    const float* Bi = (const float*)d_in[4];
    const float* Wo = (const float*)d_in[5];
    const float* Bo = (const float*)d_in[6];
    float* Out = (float*)d_out;

    char* ws = (char*)d_ws;
    _Float16* wvh = (_Float16*)(ws);                 // 73728 B
    _Float16* woh = (_Float16*)(ws + 73728);         // 73728 B -> 147456
    float*    bvf = (float*)(ws + 147456);           // 768 B   -> 148224
    float*    bof = (float*)(ws + 148224);           // 768 B   -> 148992
    float*    wkT = (float*)(ws + 148992);           // 147456 B-> 296448
    float*    ctxb = (float*)(ws + 296448);          // 196608 B-> 493056

    k_prep  <<<dim3(217),      dim3(512),  0, stream>>>(W, Bi, Wo, Bo, wvh, woh, bvf, bof, wkT);
    kA_front<<<dim3(B_ * S_),  dim3(1024), 0, stream>>>(Q, K, W, Bi, wkT, ctxb);
    k_main  <<<dim3(B_*S_*4),  dim3(1024), 0, stream>>>(V, wvh, woh, ctxb, bvf, bof, Out);
}